// Round 4
// baseline (117.237 us; speedup 1.0000x reference)
//
#include <hip/hip_runtime.h>
#include <hip/hip_cooperative_groups.h>
#include <hip/hip_fp16.h>
#include <math.h>

namespace cg = cooperative_groups;

// Problem dims (fixed by the reference)
#define BB 8
#define NN 1024
#define FF 128
#define EE 64
#define LOG2F_ 0.69314718055994531f

typedef __attribute__((ext_vector_type(4))) float f32x4;
typedef __attribute__((ext_vector_type(8))) _Float16 f16x8;

__device__ __forceinline__ float softplus_shift(float x) {
    return fmaxf(x, 0.f) + log1pf(expf(-fabsf(x))) - LOG2F_;
}

// ---------------------------------------------------------------------------
// Single fused cooperative kernel.
// Grid = 512 blocks (one per 16 output rows), 256 threads = 4 waves.
//   Pre-sync : wave 0 runs the 2-stage MFMA MLP for this block's 16 rows
//              (k pre-scaled 1/8, f16 -> ws); waves 1-3 stage the batch's
//              1024x3 positions into LDS; all waves fold the mask sum.
//   grid.sync()  (k/v of ALL rows now visible device-wide)
//   Post-sync: each wave sweeps 256 j's (16 MFMA 16x16 tiles), epilogue
//              w = s*rsqrt(r2), dir accumulate; 16-lane shuffle reduce;
//              cross-wave LDS reduce; tanh/mask/store. No partials in HBM.
// ---------------------------------------------------------------------------
__global__ __launch_bounds__(256, 2) void fused_kernel(
    const float* __restrict__ pos,  const float* __restrict__ mask,
    const float* __restrict__ h,    const float* __restrict__ W1,
    const float* __restrict__ b1,   const float* __restrict__ W2,
    const float* __restrict__ b2,
    _Float16* __restrict__ kf, _Float16* __restrict__ vf,
    float* __restrict__ out)
{
    __shared__ float    posS[NN * 3];      // 12 KB: whole batch's positions
    __shared__ _Float16 hidS[16][72];      // 2.3 KB: MLP hidden transpose
    __shared__ float    red[4][16][3];     // cross-wave partial reduce
    __shared__ float    wsum[4];

    cg::grid_group grid = cg::this_grid();

    const int t    = threadIdx.x;
    const int wave = t >> 6;
    const int lane = t & 63;
    const int bx   = blockIdx.x;
    const int b    = bx >> 6;              // batch
    const int row0 = bx << 4;              // absolute first row (b*NN + ib*16)
    const int lrow = lane & 15;
    const int kgrp = lane >> 4;

    // ---- mask sum for batch b (all waves) ----
    float pm = mask[b * NN + t]       + mask[b * NN + 256 + t]
             + mask[b * NN + 512 + t] + mask[b * NN + 768 + t];
    #pragma unroll
    for (int off = 32; off; off >>= 1) pm += __shfl_xor(pm, off, 64);
    if (lane == 0) wsum[wave] = pm;

    if (wave != 0) {
        // ---- waves 1-3: stage batch positions (3072 f32, coalesced) ----
        for (int idx = t - 64; idx < NN * 3; idx += 192)
            posS[idx] = pos[b * NN * 3 + idx];
    } else {
        // ---- wave 0: MFMA MLP for rows [row0, row0+16) ----
        // A-frags from h (f32 -> f16)
        f16x8 hf[4];
        const float* hrow = h + (size_t)(row0 + lrow) * FF;
        #pragma unroll
        for (int kk = 0; kk < 4; ++kk) {
            float tv[8];
            *(float4*)&tv[0] = *(const float4*)&hrow[kk * 32 + kgrp * 8];
            *(float4*)&tv[4] = *(const float4*)&hrow[kk * 32 + kgrp * 8 + 4];
            #pragma unroll
            for (int q = 0; q < 8; ++q) hf[kk][q] = (_Float16)tv[q];
        }
        // stage 1: pre = h @ W1 + b1 ; hid = softplus - log2 -> hidS
        #pragma unroll
        for (int c = 0; c < 4; ++c) {
            f32x4 acc1 = {0.f, 0.f, 0.f, 0.f};
            #pragma unroll
            for (int kk = 0; kk < 4; ++kk) {
                f16x8 w1f;
                #pragma unroll
                for (int q = 0; q < 8; ++q)
                    w1f[q] = (_Float16)W1[(kk * 32 + kgrp * 8 + q) * EE + c * 16 + lrow];
                acc1 = __builtin_amdgcn_mfma_f32_16x16x32_f16(hf[kk], w1f, acc1, 0, 0, 0);
            }
            const float b1c = b1[c * 16 + lrow];
            #pragma unroll
            for (int r = 0; r < 4; ++r)
                hidS[kgrp * 4 + r][c * 16 + lrow] = (_Float16)softplus_shift(acc1[r] + b1c);
        }
        // stage 2: kv = hid @ W2 + b2 ; mask; k pre-scaled 1/sqrt(E)
        f16x8 af2[2];
        #pragma unroll
        for (int kk = 0; kk < 2; ++kk)
            af2[kk] = *(const f16x8*)&hidS[lrow][kk * 32 + kgrp * 8];
        float mrow[4];
        #pragma unroll
        for (int r = 0; r < 4; ++r) mrow[r] = mask[row0 + kgrp * 4 + r];
        #pragma unroll
        for (int c2 = 0; c2 < 8; ++c2) {
            f32x4 acc2 = {0.f, 0.f, 0.f, 0.f};
            #pragma unroll
            for (int kk = 0; kk < 2; ++kk) {
                f16x8 w2f;
                #pragma unroll
                for (int q = 0; q < 8; ++q)
                    w2f[q] = (_Float16)W2[(kk * 32 + kgrp * 8 + q) * 129 + c2 * 16 + lrow];
                acc2 = __builtin_amdgcn_mfma_f32_16x16x32_f16(af2[kk], w2f, acc2, 0, 0, 0);
            }
            const float b2c = b2[c2 * 16 + lrow];
            #pragma unroll
            for (int r = 0; r < 4; ++r) {
                const int row = row0 + kgrp * 4 + r;
                const float val = (acc2[r] + b2c) * mrow[r];
                if (c2 < 4)
                    kf[row * EE + c2 * 16 + lrow] = (_Float16)(val * 0.125f);
                else
                    vf[row * EE + (c2 - 4) * 16 + lrow] = (_Float16)val;
            }
        }
    }

    __threadfence();   // make kf/vf device-visible before the grid barrier
    grid.sync();

    // ---- pairwise stage: this wave handles j in [wave*256, wave*256+256) ----
    const f16x8 afrag0 = *(const f16x8*)&kf[(row0 + lrow) * EE + kgrp * 8];
    const f16x8 afrag1 = *(const f16x8*)&kf[(row0 + lrow) * EE + 32 + kgrp * 8];

    const int ibloc = (bx & 63) << 4;      // block's first row within batch
    float pix[4], piy[4], piz[4];
    #pragma unroll
    for (int r = 0; r < 4; ++r) {
        const int il = (ibloc + kgrp * 4 + r) * 3;
        pix[r] = posS[il + 0];
        piy[r] = posS[il + 1];
        piz[r] = posS[il + 2];
    }

    float ax[4] = {0.f, 0.f, 0.f, 0.f};
    float ay[4] = {0.f, 0.f, 0.f, 0.f};
    float az[4] = {0.f, 0.f, 0.f, 0.f};

    const int jbase = wave * 256;
    for (int jt = 0; jt < 16; ++jt) {
        const int jl = jbase + jt * 16 + lrow;           // j within batch
        const int jrow = (b * NN + jl) * EE;
        const f16x8 bfrag0 = *(const f16x8*)&vf[jrow + kgrp * 8];
        const f16x8 bfrag1 = *(const f16x8*)&vf[jrow + 32 + kgrp * 8];

        f32x4 acc = {0.f, 0.f, 0.f, 0.f};
        acc = __builtin_amdgcn_mfma_f32_16x16x32_f16(afrag0, bfrag0, acc, 0, 0, 0);
        acc = __builtin_amdgcn_mfma_f32_16x16x32_f16(afrag1, bfrag1, acc, 0, 0, 0);

        const float pjx = posS[jl * 3 + 0];
        const float pjy = posS[jl * 3 + 1];
        const float pjz = posS[jl * 3 + 2];

        #pragma unroll
        for (int r = 0; r < 4; ++r) {
            const float dx = pix[r] - pjx;
            const float dy = piy[r] - pjy;
            const float dz = piz[r] - pjz;
            const float r2 = dx * dx + dy * dy + dz * dz;
            const float inv = rsqrtf(r2);
            const float w = (r2 > 1e-12f) ? acc[r] * inv : 0.f;  // diagonal -> 0
            ax[r] += dx * w;
            ay[r] += dy * w;
            az[r] += dz * w;
        }
    }

    // reduce over the 16 j-lanes sharing each i row
    #pragma unroll
    for (int off = 1; off <= 8; off <<= 1) {
        #pragma unroll
        for (int r = 0; r < 4; ++r) {
            ax[r] += __shfl_xor(ax[r], off, 64);
            ay[r] += __shfl_xor(ay[r], off, 64);
            az[r] += __shfl_xor(az[r], off, 64);
        }
    }
    if (lrow == 0) {
        #pragma unroll
        for (int r = 0; r < 4; ++r) {
            red[wave][kgrp * 4 + r][0] = ax[r];
            red[wave][kgrp * 4 + r][1] = ay[r];
            red[wave][kgrp * 4 + r][2] = az[r];
        }
    }
    __syncthreads();

    // cross-wave sum + tanh + mask + store (48 threads)
    if (t < 48) {
        const int row = t / 3, c = t % 3;
        const float s = red[0][row][c] + red[1][row][c]
                      + red[2][row][c] + red[3][row][c];
        const float inv = 1.f / (wsum[0] + wsum[1] + wsum[2] + wsum[3]);
        out[(row0 + row) * 3 + c] = tanhf(s * inv) * mask[row0 + row];
    }
}

// ---------------------------------------------------------------------------
extern "C" void kernel_launch(void* const* d_in, const int* in_sizes, int n_in,
                              void* d_out, int out_size, void* d_ws, size_t ws_size,
                              hipStream_t stream) {
    const float* pos  = (const float*)d_in[0];   // (8,1024,3)
    const float* mask = (const float*)d_in[1];   // (8,1024)
    const float* h    = (const float*)d_in[2];   // (8,1024,128)
    const float* W1   = (const float*)d_in[3];   // (128,64)
    const float* b1   = (const float*)d_in[4];   // (64,)
    const float* W2   = (const float*)d_in[5];   // (64,129)
    const float* b2   = (const float*)d_in[6];   // (129,)
    float* out = (float*)d_out;                  // (8,1024,3)

    _Float16* kf = (_Float16*)d_ws;              // 1 MB
    _Float16* vf = kf + BB * NN * EE;            // 1 MB

    void* args[] = { (void*)&pos, (void*)&mask, (void*)&h, (void*)&W1,
                     (void*)&b1, (void*)&W2, (void*)&b2,
                     (void*)&kf, (void*)&vf, (void*)&out };
    hipLaunchCooperativeKernel((const void*)fused_kernel,
                               dim3(BB * NN / 16), dim3(256),
                               args, 0, stream);
}

// Round 5
// 24.759 us; speedup vs baseline: 4.7352x; 4.7352x over previous
//
#include <hip/hip_runtime.h>
#include <hip/hip_fp16.h>
#include <math.h>

// Problem dims (fixed by the reference)
#define BB 8
#define NN 1024
#define FF 128
#define EE 64
#define LOG2F_ 0.69314718055994531f

typedef __attribute__((ext_vector_type(4))) float f32x4;
typedef __attribute__((ext_vector_type(8))) _Float16 f16x8;

__device__ __forceinline__ float softplus_shift(float x) {
    return fmaxf(x, 0.f) + log1pf(expf(-fabsf(x))) - LOG2F_;
}

// ---------------------------------------------------------------------------
// Kernel A: per-row MLP via MFMA, weights staged once per block as
// TRANSPOSED f16 in LDS so every B-fragment is a single ds_read_b128.
// 512 blocks x 256 threads (4 waves), 16 rows per block, columns split
// across waves (stage1: col-tile = wave; stage2: c2 in {2w, 2w+1}).
// ---------------------------------------------------------------------------
__global__ __launch_bounds__(256) void mlp_kernel(
    const float* __restrict__ h,  const float* __restrict__ W1,
    const float* __restrict__ b1, const float* __restrict__ W2,
    const float* __restrict__ b2, const float* __restrict__ mask,
    _Float16* __restrict__ kf, _Float16* __restrict__ vf)
{
    __shared__ _Float16 W1T[EE][FF + 8];    // [e][f]  17.4 KB
    __shared__ _Float16 W2T[2 * EE][EE + 8];// [c][d]  18.4 KB
    __shared__ _Float16 hidS[16][EE + 8];   //          2.3 KB

    const int t    = threadIdx.x;
    const int wave = t >> 6;
    const int lane = t & 63;
    const int lrow = lane & 15;
    const int kgrp = lane >> 4;
    const int row0 = blockIdx.x * 16;

    // ---- stage W1 transposed (coalesced reads, 32 elems/thread) ----
    #pragma unroll
    for (int q = 0; q < 32; ++q) {
        const int idx = t + q * 256;          // f = idx>>6, e = idx&63
        W1T[idx & 63][idx >> 6] = (_Float16)W1[idx];
    }
    // ---- stage W2 transposed (cols 0..127 only; col 128 unused) ----
    #pragma unroll
    for (int q = 0; q < 32; ++q) {
        const int idx = t + q * 256;          // d = idx>>7, c = idx&127
        const int d = idx >> 7, c = idx & 127;
        W2T[c][d] = (_Float16)W2[d * 129 + c];
    }

    // ---- A-frags: this block's 16 h rows (each wave loads redundantly) ----
    f16x8 hf[4];
    const float* hrow = h + (size_t)(row0 + lrow) * FF;
    #pragma unroll
    for (int kk = 0; kk < 4; ++kk) {
        float tv[8];
        *(float4*)&tv[0] = *(const float4*)&hrow[kk * 32 + kgrp * 8];
        *(float4*)&tv[4] = *(const float4*)&hrow[kk * 32 + kgrp * 8 + 4];
        #pragma unroll
        for (int q = 0; q < 8; ++q) hf[kk][q] = (_Float16)tv[q];
    }
    __syncthreads();

    // ---- stage 1: pre = h @ W1 + b1 ; hid = softplus - log2 ----
    {
        f32x4 acc1 = {0.f, 0.f, 0.f, 0.f};
        #pragma unroll
        for (int kk = 0; kk < 4; ++kk) {
            const f16x8 w1f = *(const f16x8*)&W1T[wave * 16 + lrow][kk * 32 + kgrp * 8];
            acc1 = __builtin_amdgcn_mfma_f32_16x16x32_f16(hf[kk], w1f, acc1, 0, 0, 0);
        }
        const float b1c = b1[wave * 16 + lrow];
        #pragma unroll
        for (int r = 0; r < 4; ++r)
            hidS[kgrp * 4 + r][wave * 16 + lrow] = (_Float16)softplus_shift(acc1[r] + b1c);
    }
    __syncthreads();

    // ---- stage 2: kv = hid @ W2 + b2 ; mask; k pre-scaled 1/sqrt(E) ----
    f16x8 af2[2];
    #pragma unroll
    for (int kk = 0; kk < 2; ++kk)
        af2[kk] = *(const f16x8*)&hidS[lrow][kk * 32 + kgrp * 8];

    float mrow[4];
    #pragma unroll
    for (int r = 0; r < 4; ++r) mrow[r] = mask[row0 + kgrp * 4 + r];

    #pragma unroll
    for (int cc = 0; cc < 2; ++cc) {
        const int c2 = wave * 2 + cc;          // 0..7 (uniform per wave)
        f32x4 acc2 = {0.f, 0.f, 0.f, 0.f};
        #pragma unroll
        for (int kk = 0; kk < 2; ++kk) {
            const f16x8 w2f = *(const f16x8*)&W2T[c2 * 16 + lrow][kk * 32 + kgrp * 8];
            acc2 = __builtin_amdgcn_mfma_f32_16x16x32_f16(af2[kk], w2f, acc2, 0, 0, 0);
        }
        const float b2c = b2[c2 * 16 + lrow];
        #pragma unroll
        for (int r = 0; r < 4; ++r) {
            const int row = row0 + kgrp * 4 + r;
            const float val = (acc2[r] + b2c) * mrow[r];
            if (c2 < 4)
                kf[row * EE + c2 * 16 + lrow] = (_Float16)(val * 0.125f);
            else
                vf[row * EE + (c2 - 4) * 16 + lrow] = (_Float16)val;
        }
    }
}

// ---------------------------------------------------------------------------
// Kernel B: pairwise stage + finalize in one kernel.
// 512 blocks x 512 threads (8 waves); block = 16 i-rows; wave w sweeps
// j in [w*128, w*128+128) as 8 MFMA 16x16 tiles (A = k rows, register-
// resident; B = v rows straight from L2-resident global). Cross-wave LDS
// reduce, then tanh/mask/store. No partial buffers.
// ---------------------------------------------------------------------------
__global__ __launch_bounds__(512) void pair_kernel(
    const _Float16* __restrict__ kf,
    const _Float16* __restrict__ vf,
    const float* __restrict__ pos,
    const float* __restrict__ mask,
    float* __restrict__ out)
{
    __shared__ float posS[NN * 3];      // 12 KB: batch positions
    __shared__ float red[8][16][3];     // cross-wave reduce
    __shared__ float wsumS[8];

    const int t    = threadIdx.x;
    const int wave = t >> 6;
    const int lane = t & 63;
    const int lrow = lane & 15;
    const int kgrp = lane >> 4;
    const int bx   = blockIdx.x;
    const int b    = bx >> 6;              // batch
    const int row0 = bx << 4;              // absolute first row
    const int ibloc = (bx & 63) << 4;      // first row within batch

    // ---- mask sum for batch b ----
    float pm = mask[b * NN + t] + mask[b * NN + 512 + t];
    #pragma unroll
    for (int off = 32; off; off >>= 1) pm += __shfl_xor(pm, off, 64);
    if (lane == 0) wsumS[wave] = pm;

    // ---- stage batch positions (3072 f32, coalesced, 6/thread) ----
    for (int idx = t; idx < NN * 3; idx += 512)
        posS[idx] = pos[b * NN * 3 + idx];
    __syncthreads();

    const float msum = wsumS[0] + wsumS[1] + wsumS[2] + wsumS[3]
                     + wsumS[4] + wsumS[5] + wsumS[6] + wsumS[7];

    // ---- A-frags: this block's 16 k rows (register-resident) ----
    const f16x8 afrag0 = *(const f16x8*)&kf[(row0 + lrow) * EE + kgrp * 8];
    const f16x8 afrag1 = *(const f16x8*)&kf[(row0 + lrow) * EE + 32 + kgrp * 8];

    float pix[4], piy[4], piz[4];
    #pragma unroll
    for (int r = 0; r < 4; ++r) {
        const int il = (ibloc + kgrp * 4 + r) * 3;
        pix[r] = posS[il + 0];
        piy[r] = posS[il + 1];
        piz[r] = posS[il + 2];
    }

    float ax[4] = {0.f, 0.f, 0.f, 0.f};
    float ay[4] = {0.f, 0.f, 0.f, 0.f};
    float az[4] = {0.f, 0.f, 0.f, 0.f};

    const int jbase = wave * 128;
    #pragma unroll 2
    for (int jt = 0; jt < 8; ++jt) {
        const int jl = jbase + jt * 16 + lrow;          // j within batch
        const int jrow = (b * NN + jl) * EE;
        const f16x8 bfrag0 = *(const f16x8*)&vf[jrow + kgrp * 8];
        const f16x8 bfrag1 = *(const f16x8*)&vf[jrow + 32 + kgrp * 8];

        f32x4 acc = {0.f, 0.f, 0.f, 0.f};
        acc = __builtin_amdgcn_mfma_f32_16x16x32_f16(afrag0, bfrag0, acc, 0, 0, 0);
        acc = __builtin_amdgcn_mfma_f32_16x16x32_f16(afrag1, bfrag1, acc, 0, 0, 0);
        // acc[r] = s(i = row0+kgrp*4+r, j = jl), pre-scaled by 1/8.

        const float pjx = posS[jl * 3 + 0];
        const float pjy = posS[jl * 3 + 1];
        const float pjz = posS[jl * 3 + 2];

        #pragma unroll
        for (int r = 0; r < 4; ++r) {
            const float dx = pix[r] - pjx;
            const float dy = piy[r] - pjy;
            const float dz = piz[r] - pjz;
            const float r2 = dx * dx + dy * dy + dz * dz;
            const float inv = rsqrtf(r2);
            const float w = (r2 > 1e-12f) ? acc[r] * inv : 0.f;  // diagonal -> 0
            ax[r] += dx * w;
            ay[r] += dy * w;
            az[r] += dz * w;
        }
    }

    // reduce over the 16 j-lanes sharing each i row
    #pragma unroll
    for (int off = 1; off <= 8; off <<= 1) {
        #pragma unroll
        for (int r = 0; r < 4; ++r) {
            ax[r] += __shfl_xor(ax[r], off, 64);
            ay[r] += __shfl_xor(ay[r], off, 64);
            az[r] += __shfl_xor(az[r], off, 64);
        }
    }
    if (lrow == 0) {
        #pragma unroll
        for (int r = 0; r < 4; ++r) {
            red[wave][kgrp * 4 + r][0] = ax[r];
            red[wave][kgrp * 4 + r][1] = ay[r];
            red[wave][kgrp * 4 + r][2] = az[r];
        }
    }
    __syncthreads();

    // cross-wave sum + tanh + mask + store (48 threads)
    if (t < 48) {
        const int row = t / 3, c = t % 3;
        float s = 0.f;
        #pragma unroll
        for (int w = 0; w < 8; ++w) s += red[w][row][c];
        out[(row0 + row) * 3 + c] = tanhf(s / msum) * mask[row0 + row];
    }
}

// ---------------------------------------------------------------------------
extern "C" void kernel_launch(void* const* d_in, const int* in_sizes, int n_in,
                              void* d_out, int out_size, void* d_ws, size_t ws_size,
                              hipStream_t stream) {
    const float* pos  = (const float*)d_in[0];   // (8,1024,3)
    const float* mask = (const float*)d_in[1];   // (8,1024)
    const float* h    = (const float*)d_in[2];   // (8,1024,128)
    const float* W1   = (const float*)d_in[3];   // (128,64)
    const float* b1   = (const float*)d_in[4];   // (64,)
    const float* W2   = (const float*)d_in[5];   // (64,129)
    const float* b2   = (const float*)d_in[6];   // (129,)
    float* out = (float*)d_out;                  // (8,1024,3)

    _Float16* kf = (_Float16*)d_ws;              // 1 MB
    _Float16* vf = kf + BB * NN * EE;            // 1 MB

    mlp_kernel<<<BB * NN / 16, 256, 0, stream>>>(h, W1, b1, W2, b2, mask, kf, vf);
    pair_kernel<<<BB * NN / 16, 512, 0, stream>>>(kf, vf, pos, mask, out);
}

// Round 6
// 24.606 us; speedup vs baseline: 4.7646x; 1.0062x over previous
//
#include <hip/hip_runtime.h>
#include <hip/hip_fp16.h>
#include <math.h>

// Problem dims (fixed by the reference)
#define BB 8
#define NN 1024
#define FF 128
#define EE 64
#define LOG2F_ 0.69314718055994531f

typedef __attribute__((ext_vector_type(4))) float f32x4;
typedef __attribute__((ext_vector_type(8))) _Float16 f16x8;

__device__ __forceinline__ float softplus_shift(float x) {
    return fmaxf(x, 0.f) + log1pf(expf(-fabsf(x))) - LOG2F_;
}

// ---------------------------------------------------------------------------
// Kernel A: per-row MLP via MFMA, weights staged once per block as
// TRANSPOSED f16 in LDS (every B-fragment = one ds_read_b128).
// 256 blocks x 512 threads (8 waves), 32 rows per block (1 block/CU).
// Wave w: row-group rg = w>>2 (16 rows), stage-1 col-tile ct = w&3,
// stage-2 c2 in {2*(w&3), 2*(w&3)+1}.
// ---------------------------------------------------------------------------
__global__ __launch_bounds__(512) void mlp_kernel(
    const float* __restrict__ h,  const float* __restrict__ W1,
    const float* __restrict__ b1, const float* __restrict__ W2,
    const float* __restrict__ b2, const float* __restrict__ mask,
    _Float16* __restrict__ kf, _Float16* __restrict__ vf)
{
    __shared__ _Float16 W1T[EE][FF + 8];     // [e][f]  17.0 KB
    __shared__ _Float16 W2T[2 * EE][EE + 8]; // [c][d]  18.0 KB
    __shared__ _Float16 hidS[32][EE + 8];    //          4.5 KB

    const int t    = threadIdx.x;
    const int wave = t >> 6;
    const int lane = t & 63;
    const int lrow = lane & 15;
    const int kgrp = lane >> 4;
    const int rg   = wave >> 2;              // row-group 0/1
    const int ct   = wave & 3;               // column task
    const int row0 = blockIdx.x * 32;
    const int rowB = row0 + rg * 16;         // this wave's 16-row strip

    // ---- stage W1 transposed (coalesced global, 16 elems/thread) ----
    #pragma unroll
    for (int q = 0; q < 16; ++q) {
        const int idx = t + q * 512;          // e = idx&63, f = idx>>6
        W1T[idx & 63][idx >> 6] = (_Float16)W1[idx];
    }
    // ---- stage W2 transposed (cols 0..127; col 128 unused) ----
    #pragma unroll
    for (int q = 0; q < 16; ++q) {
        const int idx = t + q * 512;          // d = idx>>7, c = idx&127
        const int d = idx >> 7, c = idx & 127;
        W2T[c][d] = (_Float16)W2[d * 129 + c];
    }

    // ---- A-frags: this wave's 16 h rows (f32 -> f16) ----
    f16x8 hf[4];
    const float* hrow = h + (size_t)(rowB + lrow) * FF;
    #pragma unroll
    for (int kk = 0; kk < 4; ++kk) {
        float tv[8];
        *(float4*)&tv[0] = *(const float4*)&hrow[kk * 32 + kgrp * 8];
        *(float4*)&tv[4] = *(const float4*)&hrow[kk * 32 + kgrp * 8 + 4];
        #pragma unroll
        for (int q = 0; q < 8; ++q) hf[kk][q] = (_Float16)tv[q];
    }
    __syncthreads();

    // ---- stage 1: pre = h @ W1 + b1 ; hid = softplus - log2 ----
    {
        f32x4 acc1 = {0.f, 0.f, 0.f, 0.f};
        #pragma unroll
        for (int kk = 0; kk < 4; ++kk) {
            const f16x8 w1f = *(const f16x8*)&W1T[ct * 16 + lrow][kk * 32 + kgrp * 8];
            acc1 = __builtin_amdgcn_mfma_f32_16x16x32_f16(hf[kk], w1f, acc1, 0, 0, 0);
        }
        const float b1c = b1[ct * 16 + lrow];
        #pragma unroll
        for (int r = 0; r < 4; ++r)
            hidS[rg * 16 + kgrp * 4 + r][ct * 16 + lrow] =
                (_Float16)softplus_shift(acc1[r] + b1c);
    }
    __syncthreads();

    // ---- stage 2: kv = hid @ W2 + b2 ; mask; k pre-scaled 1/sqrt(E) ----
    f16x8 af2[2];
    #pragma unroll
    for (int kk = 0; kk < 2; ++kk)
        af2[kk] = *(const f16x8*)&hidS[rg * 16 + lrow][kk * 32 + kgrp * 8];

    float mrow[4];
    #pragma unroll
    for (int r = 0; r < 4; ++r) mrow[r] = mask[rowB + kgrp * 4 + r];

    #pragma unroll
    for (int cc = 0; cc < 2; ++cc) {
        const int c2 = ct * 2 + cc;           // 0..7 (uniform per wave)
        f32x4 acc2 = {0.f, 0.f, 0.f, 0.f};
        #pragma unroll
        for (int kk = 0; kk < 2; ++kk) {
            const f16x8 w2f = *(const f16x8*)&W2T[c2 * 16 + lrow][kk * 32 + kgrp * 8];
            acc2 = __builtin_amdgcn_mfma_f32_16x16x32_f16(af2[kk], w2f, acc2, 0, 0, 0);
        }
        const float b2c = b2[c2 * 16 + lrow];
        #pragma unroll
        for (int r = 0; r < 4; ++r) {
            const int row = rowB + kgrp * 4 + r;
            const float val = (acc2[r] + b2c) * mrow[r];
            if (c2 < 4)
                kf[row * EE + c2 * 16 + lrow] = (_Float16)(val * 0.125f);
            else
                vf[row * EE + (c2 - 4) * 16 + lrow] = (_Float16)val;
        }
    }
}

// ---------------------------------------------------------------------------
// Kernel B: pairwise stage + finalize.
// 512 blocks x 512 threads (8 waves); block = 16 i-rows; wave w sweeps
// j in [w*128, w*128+128) as 8 MFMA 16x16 tiles (A = k rows, register-
// resident; B = v rows straight from L2-resident global). Guard-free
// epilogue via rsqrt(r2 + 1e-16): diagonal gives 0 * finite = 0 exactly.
// Cross-wave LDS reduce, then tanh/mask/store.
// ---------------------------------------------------------------------------
__global__ __launch_bounds__(512, 4) void pair_kernel(
    const _Float16* __restrict__ kf,
    const _Float16* __restrict__ vf,
    const float* __restrict__ pos,
    const float* __restrict__ mask,
    float* __restrict__ out)
{
    __shared__ float posS[NN * 3];      // 12 KB: batch positions
    __shared__ float red[8][16][3];     // cross-wave reduce
    __shared__ float wsumS[8];

    const int t    = threadIdx.x;
    const int wave = t >> 6;
    const int lane = t & 63;
    const int lrow = lane & 15;
    const int kgrp = lane >> 4;
    const int bx   = blockIdx.x;
    const int b    = bx >> 6;              // batch
    const int row0 = bx << 4;              // absolute first row
    const int ibloc = (bx & 63) << 4;      // first row within batch

    // ---- mask sum for batch b ----
    float pm = mask[b * NN + t] + mask[b * NN + 512 + t];
    #pragma unroll
    for (int off = 32; off; off >>= 1) pm += __shfl_xor(pm, off, 64);
    if (lane == 0) wsumS[wave] = pm;

    // ---- stage batch positions (3072 f32, coalesced, 6/thread) ----
    for (int idx = t; idx < NN * 3; idx += 512)
        posS[idx] = pos[b * NN * 3 + idx];
    __syncthreads();

    const float msum = wsumS[0] + wsumS[1] + wsumS[2] + wsumS[3]
                     + wsumS[4] + wsumS[5] + wsumS[6] + wsumS[7];

    // ---- A-frags: this block's 16 k rows (register-resident) ----
    const f16x8 afrag0 = *(const f16x8*)&kf[(row0 + lrow) * EE + kgrp * 8];
    const f16x8 afrag1 = *(const f16x8*)&kf[(row0 + lrow) * EE + 32 + kgrp * 8];

    float pix[4], piy[4], piz[4];
    #pragma unroll
    for (int r = 0; r < 4; ++r) {
        const int il = (ibloc + kgrp * 4 + r) * 3;
        pix[r] = posS[il + 0];
        piy[r] = posS[il + 1];
        piz[r] = posS[il + 2];
    }

    float ax[4] = {0.f, 0.f, 0.f, 0.f};
    float ay[4] = {0.f, 0.f, 0.f, 0.f};
    float az[4] = {0.f, 0.f, 0.f, 0.f};

    const int jbase = wave * 128;
    #pragma unroll 4
    for (int jt = 0; jt < 8; ++jt) {
        const int jl = jbase + jt * 16 + lrow;          // j within batch
        const int jrow = (b * NN + jl) * EE;
        const f16x8 bfrag0 = *(const f16x8*)&vf[jrow + kgrp * 8];
        const f16x8 bfrag1 = *(const f16x8*)&vf[jrow + 32 + kgrp * 8];

        f32x4 acc = {0.f, 0.f, 0.f, 0.f};
        acc = __builtin_amdgcn_mfma_f32_16x16x32_f16(afrag0, bfrag0, acc, 0, 0, 0);
        acc = __builtin_amdgcn_mfma_f32_16x16x32_f16(afrag1, bfrag1, acc, 0, 0, 0);
        // acc[r] = s(i = row0+kgrp*4+r, j = jl), pre-scaled by 1/8.

        const float pjx = posS[jl * 3 + 0];
        const float pjy = posS[jl * 3 + 1];
        const float pjz = posS[jl * 3 + 2];

        #pragma unroll
        for (int r = 0; r < 4; ++r) {
            const float dx = pix[r] - pjx;
            const float dy = piy[r] - pjy;
            const float dz = piz[r] - pjz;
            const float r2 = dx * dx + dy * dy + dz * dz;
            const float w = acc[r] * rsqrtf(r2 + 1e-16f);  // diagonal: 0*finite=0
            ax[r] += dx * w;
            ay[r] += dy * w;
            az[r] += dz * w;
        }
    }

    // reduce over the 16 j-lanes sharing each i row
    #pragma unroll
    for (int off = 1; off <= 8; off <<= 1) {
        #pragma unroll
        for (int r = 0; r < 4; ++r) {
            ax[r] += __shfl_xor(ax[r], off, 64);
            ay[r] += __shfl_xor(ay[r], off, 64);
            az[r] += __shfl_xor(az[r], off, 64);
        }
    }
    if (lrow == 0) {
        #pragma unroll
        for (int r = 0; r < 4; ++r) {
            red[wave][kgrp * 4 + r][0] = ax[r];
            red[wave][kgrp * 4 + r][1] = ay[r];
            red[wave][kgrp * 4 + r][2] = az[r];
        }
    }
    __syncthreads();

    // cross-wave sum + tanh + mask + store (48 threads)
    if (t < 48) {
        const int row = t / 3, c = t % 3;
        float s = 0.f;
        #pragma unroll
        for (int w = 0; w < 8; ++w) s += red[w][row][c];
        out[(row0 + row) * 3 + c] = tanhf(s / msum) * mask[row0 + row];
    }
}

// ---------------------------------------------------------------------------
extern "C" void kernel_launch(void* const* d_in, const int* in_sizes, int n_in,
                              void* d_out, int out_size, void* d_ws, size_t ws_size,
                              hipStream_t stream) {
    const float* pos  = (const float*)d_in[0];   // (8,1024,3)
    const float* mask = (const float*)d_in[1];   // (8,1024)
    const float* h    = (const float*)d_in[2];   // (8,1024,128)
    const float* W1   = (const float*)d_in[3];   // (128,64)
    const float* b1   = (const float*)d_in[4];   // (64,)
    const float* W2   = (const float*)d_in[5];   // (64,129)
    const float* b2   = (const float*)d_in[6];   // (129,)
    float* out = (float*)d_out;                  // (8,1024,3)

    _Float16* kf = (_Float16*)d_ws;              // 1 MB
    _Float16* vf = kf + BB * NN * EE;            // 1 MB

    mlp_kernel<<<BB * NN / 32, 512, 0, stream>>>(h, W1, b1, W2, b2, mask, kf, vf);
    pair_kernel<<<BB * NN / 16, 512, 0, stream>>>(kf, vf, pos, mask, out);
}

// Round 7
// 24.156 us; speedup vs baseline: 4.8534x; 1.0186x over previous
//
#include <hip/hip_runtime.h>
#include <hip/hip_fp16.h>
#include <math.h>

// Problem dims (fixed by the reference)
#define BB 8
#define NN 1024
#define FF 128
#define EE 64
#define LOG2F_ 0.69314718055994531f

typedef __attribute__((ext_vector_type(4))) float f32x4;
typedef __attribute__((ext_vector_type(8))) _Float16 f16x8;

__device__ __forceinline__ float softplus_shift(float x) {
    return fmaxf(x, 0.f) + log1pf(expf(-fabsf(x))) - LOG2F_;
}

// ---------------------------------------------------------------------------
// Kernel A: per-row MLP via MFMA, weights staged once per block as
// TRANSPOSED f16 in LDS. Staging is gather-8-to-registers (coalesced global
// reads) + ONE ds_write_b128 per chunk: 4 b128 LDS writes/thread instead of
// 32 conflicted b16 writes (the R6 LDS-pipe hotspot).
// 256 blocks x 512 threads (8 waves), 32 rows per block (1 block/CU).
// ---------------------------------------------------------------------------
__global__ __launch_bounds__(512) void mlp_kernel(
    const float* __restrict__ h,  const float* __restrict__ W1,
    const float* __restrict__ b1, const float* __restrict__ W2,
    const float* __restrict__ b2, const float* __restrict__ mask,
    _Float16* __restrict__ kf, _Float16* __restrict__ vf)
{
    __shared__ _Float16 W1T[EE][FF + 8];     // [e][f]  17.4 KB
    __shared__ _Float16 W2T[2 * EE][EE + 8]; // [c][d]  18.4 KB
    __shared__ _Float16 hidS[32][EE + 8];    //          4.6 KB

    const int t    = threadIdx.x;
    const int wave = t >> 6;
    const int lane = t & 63;
    const int lrow = lane & 15;
    const int kgrp = lane >> 4;
    const int rg   = wave >> 2;              // row-group 0/1
    const int ct   = wave & 3;               // column task
    const int row0 = blockIdx.x * 32;
    const int rowB = row0 + rg * 16;         // this wave's 16-row strip

    // ---- stage W1 transposed: thread owns (e = lane, f0 = wave*8 + q*64) ----
    // gather 8 f32 along f (coalesced across lanes), write one b128.
    #pragma unroll
    for (int q = 0; q < 2; ++q) {
        const int f0 = wave * 8 + q * 64;
        _Float16 tmp[8];
        #pragma unroll
        for (int j = 0; j < 8; ++j)
            tmp[j] = (_Float16)W1[(f0 + j) * EE + lane];
        *(f16x8*)&W1T[lane][f0] = *(const f16x8*)tmp;
    }
    // ---- stage W2 transposed: thread owns (c = q*64 + lane, d0 = wave*8) ----
    #pragma unroll
    for (int q = 0; q < 2; ++q) {
        const int c  = q * 64 + lane;
        const int d0 = wave * 8;
        _Float16 tmp[8];
        #pragma unroll
        for (int j = 0; j < 8; ++j)
            tmp[j] = (_Float16)W2[(d0 + j) * 129 + c];
        *(f16x8*)&W2T[c][d0] = *(const f16x8*)tmp;
    }

    // ---- A-frags: this wave's 16 h rows (f32 -> f16) ----
    f16x8 hf[4];
    const float* hrow = h + (size_t)(rowB + lrow) * FF;
    #pragma unroll
    for (int kk = 0; kk < 4; ++kk) {
        float tv[8];
        *(float4*)&tv[0] = *(const float4*)&hrow[kk * 32 + kgrp * 8];
        *(float4*)&tv[4] = *(const float4*)&hrow[kk * 32 + kgrp * 8 + 4];
        #pragma unroll
        for (int q = 0; q < 8; ++q) hf[kk][q] = (_Float16)tv[q];
    }
    __syncthreads();

    // ---- stage 1: pre = h @ W1 + b1 ; hid = softplus - log2 ----
    {
        f32x4 acc1 = {0.f, 0.f, 0.f, 0.f};
        #pragma unroll
        for (int kk = 0; kk < 4; ++kk) {
            const f16x8 w1f = *(const f16x8*)&W1T[ct * 16 + lrow][kk * 32 + kgrp * 8];
            acc1 = __builtin_amdgcn_mfma_f32_16x16x32_f16(hf[kk], w1f, acc1, 0, 0, 0);
        }
        const float b1c = b1[ct * 16 + lrow];
        #pragma unroll
        for (int r = 0; r < 4; ++r)
            hidS[rg * 16 + kgrp * 4 + r][ct * 16 + lrow] =
                (_Float16)softplus_shift(acc1[r] + b1c);
    }
    __syncthreads();

    // ---- stage 2: kv = hid @ W2 + b2 ; mask; k pre-scaled 1/sqrt(E) ----
    f16x8 af2[2];
    #pragma unroll
    for (int kk = 0; kk < 2; ++kk)
        af2[kk] = *(const f16x8*)&hidS[rg * 16 + lrow][kk * 32 + kgrp * 8];

    float mrow[4];
    #pragma unroll
    for (int r = 0; r < 4; ++r) mrow[r] = mask[rowB + kgrp * 4 + r];

    #pragma unroll
    for (int cc = 0; cc < 2; ++cc) {
        const int c2 = ct * 2 + cc;           // 0..7 (uniform per wave)
        f32x4 acc2 = {0.f, 0.f, 0.f, 0.f};
        #pragma unroll
        for (int kk = 0; kk < 2; ++kk) {
            const f16x8 w2f = *(const f16x8*)&W2T[c2 * 16 + lrow][kk * 32 + kgrp * 8];
            acc2 = __builtin_amdgcn_mfma_f32_16x16x32_f16(af2[kk], w2f, acc2, 0, 0, 0);
        }
        const float b2c = b2[c2 * 16 + lrow];
        #pragma unroll
        for (int r = 0; r < 4; ++r) {
            const int row = rowB + kgrp * 4 + r;
            const float val = (acc2[r] + b2c) * mrow[r];
            if (c2 < 4)
                kf[row * EE + c2 * 16 + lrow] = (_Float16)(val * 0.125f);
            else
                vf[row * EE + (c2 - 4) * 16 + lrow] = (_Float16)val;
        }
    }
}

// ---------------------------------------------------------------------------
// Kernel B: pairwise stage + finalize (unchanged from R6).
// 512 blocks x 512 threads (8 waves); block = 16 i-rows; wave w sweeps
// j in [w*128, w*128+128) as 8 MFMA 16x16 tiles. Guard-free epilogue via
// rsqrt(r2 + 1e-16). Cross-wave LDS reduce, then tanh/mask/store.
// ---------------------------------------------------------------------------
__global__ __launch_bounds__(512, 4) void pair_kernel(
    const _Float16* __restrict__ kf,
    const _Float16* __restrict__ vf,
    const float* __restrict__ pos,
    const float* __restrict__ mask,
    float* __restrict__ out)
{
    __shared__ float posS[NN * 3];      // 12 KB: batch positions
    __shared__ float red[8][16][3];     // cross-wave reduce
    __shared__ float wsumS[8];

    const int t    = threadIdx.x;
    const int wave = t >> 6;
    const int lane = t & 63;
    const int lrow = lane & 15;
    const int kgrp = lane >> 4;
    const int bx   = blockIdx.x;
    const int b    = bx >> 6;              // batch
    const int row0 = bx << 4;              // absolute first row
    const int ibloc = (bx & 63) << 4;      // first row within batch

    // ---- mask sum for batch b ----
    float pm = mask[b * NN + t] + mask[b * NN + 512 + t];
    #pragma unroll
    for (int off = 32; off; off >>= 1) pm += __shfl_xor(pm, off, 64);
    if (lane == 0) wsumS[wave] = pm;

    // ---- stage batch positions (3072 f32, coalesced, 6/thread) ----
    for (int idx = t; idx < NN * 3; idx += 512)
        posS[idx] = pos[b * NN * 3 + idx];
    __syncthreads();

    const float msum = wsumS[0] + wsumS[1] + wsumS[2] + wsumS[3]
                     + wsumS[4] + wsumS[5] + wsumS[6] + wsumS[7];

    // ---- A-frags: this block's 16 k rows (register-resident) ----
    const f16x8 afrag0 = *(const f16x8*)&kf[(row0 + lrow) * EE + kgrp * 8];
    const f16x8 afrag1 = *(const f16x8*)&kf[(row0 + lrow) * EE + 32 + kgrp * 8];

    float pix[4], piy[4], piz[4];
    #pragma unroll
    for (int r = 0; r < 4; ++r) {
        const int il = (ibloc + kgrp * 4 + r) * 3;
        pix[r] = posS[il + 0];
        piy[r] = posS[il + 1];
        piz[r] = posS[il + 2];
    }

    float ax[4] = {0.f, 0.f, 0.f, 0.f};
    float ay[4] = {0.f, 0.f, 0.f, 0.f};
    float az[4] = {0.f, 0.f, 0.f, 0.f};

    const int jbase = wave * 128;
    #pragma unroll 4
    for (int jt = 0; jt < 8; ++jt) {
        const int jl = jbase + jt * 16 + lrow;          // j within batch
        const int jrow = (b * NN + jl) * EE;
        const f16x8 bfrag0 = *(const f16x8*)&vf[jrow + kgrp * 8];
        const f16x8 bfrag1 = *(const f16x8*)&vf[jrow + 32 + kgrp * 8];

        f32x4 acc = {0.f, 0.f, 0.f, 0.f};
        acc = __builtin_amdgcn_mfma_f32_16x16x32_f16(afrag0, bfrag0, acc, 0, 0, 0);
        acc = __builtin_amdgcn_mfma_f32_16x16x32_f16(afrag1, bfrag1, acc, 0, 0, 0);
        // acc[r] = s(i = row0+kgrp*4+r, j = jl), pre-scaled by 1/8.

        const float pjx = posS[jl * 3 + 0];
        const float pjy = posS[jl * 3 + 1];
        const float pjz = posS[jl * 3 + 2];

        #pragma unroll
        for (int r = 0; r < 4; ++r) {
            const float dx = pix[r] - pjx;
            const float dy = piy[r] - pjy;
            const float dz = piz[r] - pjz;
            const float r2 = dx * dx + dy * dy + dz * dz;
            const float w = acc[r] * rsqrtf(r2 + 1e-16f);  // diagonal: 0*finite=0
            ax[r] += dx * w;
            ay[r] += dy * w;
            az[r] += dz * w;
        }
    }

    // reduce over the 16 j-lanes sharing each i row
    #pragma unroll
    for (int off = 1; off <= 8; off <<= 1) {
        #pragma unroll
        for (int r = 0; r < 4; ++r) {
            ax[r] += __shfl_xor(ax[r], off, 64);
            ay[r] += __shfl_xor(ay[r], off, 64);
            az[r] += __shfl_xor(az[r], off, 64);
        }
    }
    if (lrow == 0) {
        #pragma unroll
        for (int r = 0; r < 4; ++r) {
            red[wave][kgrp * 4 + r][0] = ax[r];
            red[wave][kgrp * 4 + r][1] = ay[r];
            red[wave][kgrp * 4 + r][2] = az[r];
        }
    }
    __syncthreads();

    // cross-wave sum + tanh + mask + store (48 threads)
    if (t < 48) {
        const int row = t / 3, c = t % 3;
        float s = 0.f;
        #pragma unroll
        for (int w = 0; w < 8; ++w) s += red[w][row][c];
        out[(row0 + row) * 3 + c] = tanhf(s / msum) * mask[row0 + row];
    }
}

// ---------------------------------------------------------------------------
extern "C" void kernel_launch(void* const* d_in, const int* in_sizes, int n_in,
                              void* d_out, int out_size, void* d_ws, size_t ws_size,
                              hipStream_t stream) {
    const float* pos  = (const float*)d_in[0];   // (8,1024,3)
    const float* mask = (const float*)d_in[1];   // (8,1024)
    const float* h    = (const float*)d_in[2];   // (8,1024,128)
    const float* W1   = (const float*)d_in[3];   // (128,64)
    const float* b1   = (const float*)d_in[4];   // (64,)
    const float* W2   = (const float*)d_in[5];   // (64,129)
    const float* b2   = (const float*)d_in[6];   // (129,)
    float* out = (float*)d_out;                  // (8,1024,3)

    _Float16* kf = (_Float16*)d_ws;              // 1 MB
    _Float16* vf = kf + BB * NN * EE;            // 1 MB

    mlp_kernel<<<BB * NN / 32, 512, 0, stream>>>(h, W1, b1, W2, b2, mask, kf, vf);
    pair_kernel<<<BB * NN / 16, 512, 0, stream>>>(kf, vf, pos, mask, out);
}